// Round 3
// baseline (55.944 us; speedup 1.0000x reference)
//
#include <hip/hip_runtime.h>
#include <stdint.h>

// Problem constants (from reference): x shape [T*B, C, H, W] = [256, 128, 32, 32]
static constexpr int   T_  = 8;
static constexpr int   C_  = 128;
static constexpr int   N_  = 32 * 128 * 32 * 32;  // B*C*H*W = 4194304 sites
static constexpr int   NBLK_ = N_ / 4 / 256;      // 4096 blocks, 4 sites/thread
static constexpr float LR_ = 0.1f;

// Native clang vector types (usable with __builtin_nontemporal_*)
typedef float v4f __attribute__((ext_vector_type(4)));

// ---------------------------------------------------------------------------
// K1: IF recurrence over T, pack spike bits, per-block new_thre partial.
// Each thread owns 4 consecutive sites (v4f loads). A block covers 1024
// consecutive sites = exactly one (b,c) H*W plane, so channel = blockIdx&127.
// part[blockIdx] is written unconditionally -> no memset, no atomics.
// ---------------------------------------------------------------------------
template <bool PACK>
__global__ __launch_bounds__(256) void k_fwd(const float* __restrict__ x,
                                             const float* __restrict__ thresh,
                                             uint8_t* __restrict__ spk,
                                             float* __restrict__ part) {
    const float thre = thresh[0];
    const int e4   = blockIdx.x * 256 + threadIdx.x;
    const int base = e4 * 4;

    float    mem[4];
    int      cnt[4] = {0, 0, 0, 0};
    unsigned pb[4]  = {0, 0, 0, 0};
#pragma unroll
    for (int i = 0; i < 4; ++i) mem[i] = 0.5f * thre;

#pragma unroll
    for (int t = 0; t < T_; ++t) {
        const v4f xv = __builtin_nontemporal_load(
            reinterpret_cast<const v4f*>(x + (size_t)t * N_ + base));
#pragma unroll
        for (int i = 0; i < 4; ++i) {
            mem[i] += xv[i];
            if (mem[i] - thre >= 0.0f) {   // heaviside(mem - cur)
                mem[i] -= thre;            // mem - s*cur
                pb[i] |= (1u << t);
                cnt[i]++;
            }
        }
    }

    if (PACK) {
        const unsigned packed = pb[0] | (pb[1] << 8) | (pb[2] << 16) | (pb[3] << 24);
        reinterpret_cast<unsigned*>(spk)[e4] = packed;
    }

    // per-site new_thre, summed over this thread's 4 sites
    float local = 0.0f;
#pragma unroll
    for (int i = 0; i < 4; ++i) {
        const float compen_mem = mem[i] - 0.5f * thre;
        const float cv = fminf(compen_mem + (float)cnt[i] * thre, (float)T_ * thre);
        if (cv > 0.0f && cnt[i] > 0) local += cv / (float)cnt[i];
    }

    // wave64 shuffle reduce, then 4 wave partials via LDS, one store per block
#pragma unroll
    for (int off = 32; off > 0; off >>= 1) local += __shfl_down(local, off, 64);
    __shared__ float wpart[4];
    const int lane = threadIdx.x & 63;
    const int wid  = threadIdx.x >> 6;
    if (lane == 0) wpart[wid] = local;
    __syncthreads();
    if (threadIdx.x == 0) {
        part[blockIdx.x] = wpart[0] + wpart[1] + wpart[2] + wpart[3];
    }
}

// ---------------------------------------------------------------------------
// Scalar prologue shared by both output kernels: every block redundantly
// reduces the 4096 partials (channel = idx & 127, 32 groups per channel),
// applies the masked-diff mean over channels, returns thre + update.
// Loads are coalesced and L2-resident (16 KB).
// ---------------------------------------------------------------------------
__device__ __forceinline__ float compute_scalar(const float* __restrict__ part,
                                                const float thre,
                                                float* s_red) {
    float v = 0.0f;
    if (threadIdx.x < C_) {
        float sum = 0.0f;
#pragma unroll
        for (int g = 0; g < NBLK_ / C_; ++g) sum += part[g * C_ + threadIdx.x];
        const float ub = sum * (1.0f / 32768.0f);  // mean over B*H*W
        v = (thre > ub) ? (ub - thre) : 0.0f;      // diff * mask
    }
#pragma unroll
    for (int off = 32; off > 0; off >>= 1) v += __shfl_down(v, off, 64);
    if ((threadIdx.x & 63) == 0) s_red[1 + (threadIdx.x >> 6)] = v;
    __syncthreads();
    if (threadIdx.x == 0) {
        const float update =
            LR_ * 2.0f * (s_red[1] + s_red[2] + s_red[3] + s_red[4]) * (1.0f / (float)C_);
        s_red[0] = thre + update;
    }
    __syncthreads();
    return s_red[0];
}

// ---------------------------------------------------------------------------
// K2 (packed path): out[t, site] = spike_bit ? scalar : 0
// ---------------------------------------------------------------------------
__global__ __launch_bounds__(256) void k_out(const uint8_t* __restrict__ spk,
                                             const float* __restrict__ part,
                                             const float* __restrict__ thresh,
                                             float* __restrict__ out) {
    __shared__ float s_red[5];
    const float s = compute_scalar(part, thresh[0], s_red);

    const int e4   = blockIdx.x * 256 + threadIdx.x;
    const int base = e4 * 4;
    const unsigned packed = reinterpret_cast<const unsigned*>(spk)[e4];
    const unsigned pb[4] = {packed & 0xffu, (packed >> 8) & 0xffu,
                            (packed >> 16) & 0xffu, (packed >> 24) & 0xffu};
#pragma unroll
    for (int t = 0; t < T_; ++t) {
        v4f o;
        o.x = ((pb[0] >> t) & 1) ? s : 0.0f;
        o.y = ((pb[1] >> t) & 1) ? s : 0.0f;
        o.z = ((pb[2] >> t) & 1) ? s : 0.0f;
        o.w = ((pb[3] >> t) & 1) ? s : 0.0f;
        __builtin_nontemporal_store(o, reinterpret_cast<v4f*>(out + (size_t)t * N_ + base));
    }
}

// ---------------------------------------------------------------------------
// K2 fallback (ws too small for spike pack): recompute recurrence from x
// ---------------------------------------------------------------------------
__global__ __launch_bounds__(256) void k_out_recompute(const float* __restrict__ x,
                                                       const float* __restrict__ part,
                                                       const float* __restrict__ thresh,
                                                       float* __restrict__ out) {
    __shared__ float s_red[5];
    const float thre = thresh[0];
    const float s = compute_scalar(part, thre, s_red);

    const int e4   = blockIdx.x * 256 + threadIdx.x;
    const int base = e4 * 4;
    float mem[4];
#pragma unroll
    for (int i = 0; i < 4; ++i) mem[i] = 0.5f * thre;
#pragma unroll
    for (int t = 0; t < T_; ++t) {
        const v4f xv = __builtin_nontemporal_load(
            reinterpret_cast<const v4f*>(x + (size_t)t * N_ + base));
        v4f o;
#pragma unroll
        for (int i = 0; i < 4; ++i) {
            mem[i] += xv[i];
            if (mem[i] - thre >= 0.0f) {
                mem[i] -= thre;
                o[i] = s;
            } else {
                o[i] = 0.0f;
            }
        }
        __builtin_nontemporal_store(o, reinterpret_cast<v4f*>(out + (size_t)t * N_ + base));
    }
}

extern "C" void kernel_launch(void* const* d_in, const int* in_sizes, int n_in,
                              void* d_out, int out_size, void* d_ws, size_t ws_size,
                              hipStream_t stream) {
    const float* x      = (const float*)d_in[0];
    const float* thresh = (const float*)d_in[1];
    float*       out    = (float*)d_out;

    // ws layout: [0, 16K) part[4096] | [16K, 16K + N_) packed spikes
    float*   part = (float*)d_ws;
    uint8_t* spk  = (uint8_t*)d_ws + NBLK_ * sizeof(float);
    const bool pack = ws_size >= (size_t)(NBLK_ * sizeof(float) + N_);

    if (pack) {
        k_fwd<true><<<NBLK_, 256, 0, stream>>>(x, thresh, spk, part);
        k_out<<<NBLK_, 256, 0, stream>>>(spk, part, thresh, out);
    } else {
        k_fwd<false><<<NBLK_, 256, 0, stream>>>(x, thresh, nullptr, part);
        k_out_recompute<<<NBLK_, 256, 0, stream>>>(x, part, thresh, out);
    }
}